// Round 4
// baseline (80.710 us; speedup 1.0000x reference)
//
#include <hip/hip_runtime.h>
#include <cstdint>

#define NV 8192
#define CAP 512   // max neighbors tracked per row (mean ~33, 512 is ~84 sigma safe)

typedef int v4i __attribute__((ext_vector_type(4)));

__global__ __launch_bounds__(256) void devgnn_kernel(
    const float* __restrict__ x,
    const float* __restrict__ nodes,
    const int*   __restrict__ adj,          // [NV][NV] int32 bool
    const float* __restrict__ Wphi1,   const float* __restrict__ bphi1,
    const float* __restrict__ Wtheta1, const float* __restrict__ btheta1,
    const float* __restrict__ Wphi2,   const float* __restrict__ bphi2,
    const float* __restrict__ Wtheta2, const float* __restrict__ btheta2,
    const float* __restrict__ Wphi3,   const float* __restrict__ bphi3,
    const float* __restrict__ Wtheta3, const float* __restrict__ btheta3,
    float* __restrict__ out)
{
    const int i = blockIdx.x;
    const int t = threadIdx.x;

    __shared__ float4 s_p[CAP];     // gathered neighbor coords
    __shared__ int    s_cnt;
    __shared__ float  sh_h1;        // layer-1 activation of node i
    __shared__ float  sh_agg3;      // layer-3 aggregate of node i

    // ---- preload per-lane channel weights (overlaps with scan) ----
    float mw0 = 0.f, mw1 = 0.f, mw2 = 0.f;
    if (t < 64) {                   // layer-2 channel t; Wtheta2 is [3][64] row-major
        mw0 = Wtheta2[t];
        mw1 = Wtheta2[64 + t];
        mw2 = Wtheta2[128 + t];
    } else if (t == 64) {
        mw0 = Wtheta1[0]; mw1 = Wtheta1[1]; mw2 = Wtheta1[2];
    } else if (t == 65) {
        mw0 = Wtheta3[0]; mw1 = Wtheta3[1]; mw2 = Wtheta3[2];
    }

    if (t == 0) s_cnt = 0;
    __syncthreads();

    // ---- Phase 1: stream adjacency row (32 KB int32), gather coords ----
    // 8192 int32 / row -> 2048 int4 chunks -> 8 per thread.
    // ~99.4% of chunks are all-zero: single-test fast path.
    // nontemporal: 256 MB stream must not evict the hot 96 KB nodes table.
    const v4i* row = reinterpret_cast<const v4i*>(adj + (size_t)i * NV);
    #pragma unroll
    for (int r = 0; r < 8; ++r) {
        const int idx4 = t + r * 256;
        const v4i v = __builtin_nontemporal_load(&row[idx4]);
        if ((v[0] | v[1] | v[2] | v[3]) == 0) continue;
        const int base = idx4 * 4;
        #pragma unroll
        for (int k = 0; k < 4; ++k) {
            if (v[k]) {
                const int p = atomicAdd(&s_cnt, 1);
                if (p < CAP) {
                    const int j = base + k;
                    s_p[p] = make_float4(nodes[3 * j + 0],
                                         nodes[3 * j + 1],
                                         nodes[3 * j + 2], 0.f);
                }
            }
        }
    }
    __syncthreads();
    const int cnt = (s_cnt < CAP) ? s_cnt : CAP;

    // ---- Phase 2: 66 channel-mins over the neighbor list ----
    // node i's own coords: uniform address -> scalar loads (broadcast, free)
    const float qx = nodes[3 * i + 0];
    const float qy = nodes[3 * i + 1];
    const float qz = nodes[3 * i + 2];

    float m = 1e30f, tp_i = 0.f;
    if (t < 66) {
        #pragma unroll 4
        for (int k = 0; k < cnt; ++k) {
            const float4 c = s_p[k];            // LDS broadcast across lanes
            m = fminf(m, c.x * mw0 + c.y * mw1 + c.z * mw2);
        }
        tp_i = qx * mw0 + qy * mw1 + qz * mw2;

        if (t == 64) {
            const float agg1 = tp_i - m + btheta1[0];
            sh_h1 = fmaxf(0.f, x[i] * Wphi1[0] + bphi1[0] + agg1);
        } else if (t == 65) {
            sh_agg3 = tp_i - m + btheta3[0];
        }
    }
    __syncthreads();

    // ---- Phase 3: layer-2 epilogue + layer-3 dot + sigmoid ----
    if (t < 64) {
        const float agg2 = tp_i - m + btheta2[t];
        const float h2 = fmaxf(0.f, sh_h1 * Wphi2[t] + bphi2[t] + agg2);
        float partial = h2 * Wphi3[t];
        #pragma unroll
        for (int d = 32; d >= 1; d >>= 1)
            partial += __shfl_xor(partial, d, 64);
        if (t == 0) {
            const float val = partial + bphi3[0] + sh_agg3;
            out[i] = 1.f / (1.f + expf(-val));
        }
    }
}

extern "C" void kernel_launch(void* const* d_in, const int* in_sizes, int n_in,
                              void* d_out, int out_size, void* d_ws, size_t ws_size,
                              hipStream_t stream) {
    const float* x         = (const float*)d_in[0];
    const float* nodes     = (const float*)d_in[1];
    const int*   adj       = (const int*)d_in[2];
    const float* Wphi1     = (const float*)d_in[3];
    const float* bphi1     = (const float*)d_in[4];
    const float* Wtheta1   = (const float*)d_in[5];
    const float* btheta1   = (const float*)d_in[6];
    const float* Wphi2     = (const float*)d_in[7];
    const float* bphi2     = (const float*)d_in[8];
    const float* Wtheta2   = (const float*)d_in[9];
    const float* btheta2   = (const float*)d_in[10];
    const float* Wphi3     = (const float*)d_in[11];
    const float* bphi3     = (const float*)d_in[12];
    const float* Wtheta3   = (const float*)d_in[13];
    const float* btheta3   = (const float*)d_in[14];
    float* out = (float*)d_out;

    devgnn_kernel<<<NV, 256, 0, stream>>>(
        x, nodes, adj,
        Wphi1, bphi1, Wtheta1, btheta1,
        Wphi2, bphi2, Wtheta2, btheta2,
        Wphi3, bphi3, Wtheta3, btheta3,
        out);
}

// Round 5
// 48.801 us; speedup vs baseline: 1.6538x; 1.6538x over previous
//
#include <hip/hip_runtime.h>
#include <cstdint>

#define NV 8192
#define CAP 512   // max neighbors tracked per row (mean ~33, 512 is ~84 sigma safe)

typedef int v4i __attribute__((ext_vector_type(4)));

__global__ __launch_bounds__(256) void devgnn_kernel(
    const float* __restrict__ x,
    const float* __restrict__ nodes,
    const int*   __restrict__ adj,          // [NV][NV] int32 bool
    const float* __restrict__ Wphi1,   const float* __restrict__ bphi1,
    const float* __restrict__ Wtheta1, const float* __restrict__ btheta1,
    const float* __restrict__ Wphi2,   const float* __restrict__ bphi2,
    const float* __restrict__ Wtheta2, const float* __restrict__ btheta2,
    const float* __restrict__ Wphi3,   const float* __restrict__ bphi3,
    const float* __restrict__ Wtheta3, const float* __restrict__ btheta3,
    float* __restrict__ out)
{
    const int i = blockIdx.x;
    const int t = threadIdx.x;

    __shared__ int    s_nb[CAP];    // neighbor indices
    __shared__ float4 s_p[CAP];     // gathered neighbor coords
    __shared__ int    s_cnt;
    __shared__ float  sh_h1;        // layer-1 activation of node i
    __shared__ float  sh_agg3;      // layer-3 aggregate of node i

    // ---- preload per-lane channel weights (overlaps with scan) ----
    float mw0 = 0.f, mw1 = 0.f, mw2 = 0.f;
    if (t < 64) {                   // layer-2 channel t; Wtheta2 is [3][64] row-major
        mw0 = Wtheta2[t];
        mw1 = Wtheta2[64 + t];
        mw2 = Wtheta2[128 + t];
    } else if (t == 64) {
        mw0 = Wtheta1[0]; mw1 = Wtheta1[1]; mw2 = Wtheta1[2];
    } else if (t == 65) {
        mw0 = Wtheta3[0]; mw1 = Wtheta3[1]; mw2 = Wtheta3[2];
    }

    if (t == 0) s_cnt = 0;
    __syncthreads();

    // ---- Phase 1a: stream the 32 KB row with ZERO control flow ----
    // 8 back-to-back dwordx4 loads per thread -> one vmcnt wait, full ILP.
    const v4i* row = reinterpret_cast<const v4i*>(adj + (size_t)i * NV);
    v4i v[8];
    #pragma unroll
    for (int r = 0; r < 8; ++r)
        v[r] = row[t + r * 256];

    // ---- Phase 1b: expand the rare nonzero chunks (registers only) ----
    #pragma unroll
    for (int r = 0; r < 8; ++r) {
        if ((v[r][0] | v[r][1] | v[r][2] | v[r][3]) != 0) {
            const int base = (t + r * 256) * 4;
            #pragma unroll
            for (int k = 0; k < 4; ++k) {
                if (v[r][k]) {
                    const int p = atomicAdd(&s_cnt, 1);
                    if (p < CAP) s_nb[p] = base + k;
                }
            }
        }
    }
    __syncthreads();
    const int cnt = (s_cnt < CAP) ? s_cnt : CAP;

    // ---- Phase 2: parallel gather of neighbor coordinates ----
    for (int k = t; k < cnt; k += 256) {
        const int j = s_nb[k];
        s_p[k] = make_float4(nodes[3 * j + 0],
                             nodes[3 * j + 1],
                             nodes[3 * j + 2], 0.f);
    }
    __syncthreads();

    // ---- Phase 3: 66 channel-mins over the neighbor list ----
    const float qx = nodes[3 * i + 0];   // uniform address -> scalar broadcast
    const float qy = nodes[3 * i + 1];
    const float qz = nodes[3 * i + 2];

    float m = 1e30f, tp_i = 0.f;
    if (t < 66) {
        #pragma unroll 4
        for (int k = 0; k < cnt; ++k) {
            const float4 c = s_p[k];            // LDS broadcast across lanes
            m = fminf(m, c.x * mw0 + c.y * mw1 + c.z * mw2);
        }
        tp_i = qx * mw0 + qy * mw1 + qz * mw2;

        if (t == 64) {
            const float agg1 = tp_i - m + btheta1[0];
            sh_h1 = fmaxf(0.f, x[i] * Wphi1[0] + bphi1[0] + agg1);
        } else if (t == 65) {
            sh_agg3 = tp_i - m + btheta3[0];
        }
    }
    __syncthreads();

    // ---- Phase 4: layer-2 epilogue + layer-3 dot + sigmoid ----
    if (t < 64) {
        const float agg2 = tp_i - m + btheta2[t];
        const float h2 = fmaxf(0.f, sh_h1 * Wphi2[t] + bphi2[t] + agg2);
        float partial = h2 * Wphi3[t];
        #pragma unroll
        for (int d = 32; d >= 1; d >>= 1)
            partial += __shfl_xor(partial, d, 64);
        if (t == 0) {
            const float val = partial + bphi3[0] + sh_agg3;
            out[i] = 1.f / (1.f + expf(-val));
        }
    }
}

extern "C" void kernel_launch(void* const* d_in, const int* in_sizes, int n_in,
                              void* d_out, int out_size, void* d_ws, size_t ws_size,
                              hipStream_t stream) {
    const float* x         = (const float*)d_in[0];
    const float* nodes     = (const float*)d_in[1];
    const int*   adj       = (const int*)d_in[2];
    const float* Wphi1     = (const float*)d_in[3];
    const float* bphi1     = (const float*)d_in[4];
    const float* Wtheta1   = (const float*)d_in[5];
    const float* btheta1   = (const float*)d_in[6];
    const float* Wphi2     = (const float*)d_in[7];
    const float* bphi2     = (const float*)d_in[8];
    const float* Wtheta2   = (const float*)d_in[9];
    const float* btheta2   = (const float*)d_in[10];
    const float* Wphi3     = (const float*)d_in[11];
    const float* bphi3     = (const float*)d_in[12];
    const float* Wtheta3   = (const float*)d_in[13];
    const float* btheta3   = (const float*)d_in[14];
    float* out = (float*)d_out;

    devgnn_kernel<<<NV, 256, 0, stream>>>(
        x, nodes, adj,
        Wphi1, bphi1, Wtheta1, btheta1,
        Wphi2, bphi2, Wtheta2, btheta2,
        Wphi3, bphi3, Wtheta3, btheta3,
        out);
}

// Round 6
// 48.078 us; speedup vs baseline: 1.6787x; 1.0150x over previous
//
#include <hip/hip_runtime.h>
#include <cstdint>

#define NV 8192
#define CAP 192   // per-row neighbor cap (mean ~33.8, sigma ~5.8 -> 27 sigma margin)

typedef int v4i __attribute__((ext_vector_type(4)));

__global__ __launch_bounds__(256) void devgnn_kernel(
    const float* __restrict__ x,
    const float* __restrict__ nodes,
    const int*   __restrict__ adj,          // [NV][NV] int32 bool
    const float* __restrict__ Wphi1,   const float* __restrict__ bphi1,
    const float* __restrict__ Wtheta1, const float* __restrict__ btheta1,
    const float* __restrict__ Wphi2,   const float* __restrict__ bphi2,
    const float* __restrict__ Wtheta2, const float* __restrict__ btheta2,
    const float* __restrict__ Wphi3,   const float* __restrict__ bphi3,
    const float* __restrict__ Wtheta3, const float* __restrict__ btheta3,
    float* __restrict__ out)
{
    const int t    = threadIdx.x;
    const int w    = t >> 6;                // wave id 0..3
    const int lane = t & 63;
    const int i    = blockIdx.x * 4 + w;    // this wave's row

    // wave-private LDS slices: no __syncthreads anywhere (same-wave LDS
    // ops are issued in order; compiler inserts lgkmcnt for value deps)
    __shared__ int    s_nb[4][CAP];
    __shared__ float4 s_p[4][CAP];
    __shared__ int    s_cnt[4];

    if (lane == 0) s_cnt[w] = 0;

    // ---- per-lane channel weights: lane = layer-2 channel ----
    const float mw0 = Wtheta2[lane];        // Wtheta2 is [3][64] row-major
    const float mw1 = Wtheta2[64 + lane];
    const float mw2 = Wtheta2[128 + lane];
    const float w10 = Wtheta1[0], w11 = Wtheta1[1], w12 = Wtheta1[2];
    const float w30 = Wtheta3[0], w31 = Wtheta3[1], w32 = Wtheta3[2];

    const v4i* row = reinterpret_cast<const v4i*>(adj + (size_t)i * NV);

    // ---- scan: 2048 int4 per row, 4 batches of 8 int4/lane, dbuf ----
    v4i va[8], vb[8];

    #pragma unroll
    for (int r = 0; r < 8; ++r) va[r] = row[lane + r * 64];            // batch 0
    #pragma unroll
    for (int r = 0; r < 8; ++r) vb[r] = row[512 + lane + r * 64];      // batch 1

    auto expand = [&](const v4i* v, int batch) {
        #pragma unroll
        for (int r = 0; r < 8; ++r) {
            const v4i vv = v[r];
            if ((vv[0] | vv[1] | vv[2] | vv[3]) != 0) {
                const int base = (batch * 512 + lane + r * 64) * 4;
                #pragma unroll
                for (int k = 0; k < 4; ++k) {
                    if (vv[k]) {
                        const int p = atomicAdd(&s_cnt[w], 1);
                        if (p < CAP) s_nb[w][p] = base + k;
                    }
                }
            }
        }
    };

    expand(va, 0);
    #pragma unroll
    for (int r = 0; r < 8; ++r) va[r] = row[1024 + lane + r * 64];     // batch 2
    expand(vb, 1);
    #pragma unroll
    for (int r = 0; r < 8; ++r) vb[r] = row[1536 + lane + r * 64];     // batch 3
    expand(va, 2);
    expand(vb, 3);

    int cnt = s_cnt[w];
    cnt = (cnt < CAP) ? cnt : CAP;

    // ---- gather neighbor coords (one round, scattered L2 hits) ----
    for (int k = lane; k < cnt; k += 64) {
        const int j = s_nb[w][k];
        s_p[w][k] = make_float4(nodes[3 * j + 0],
                                nodes[3 * j + 1],
                                nodes[3 * j + 2], 0.f);
    }

    // ---- channel mins: lane = channel for layer 2 (broadcast reads) ----
    float m2 = 1e30f;
    for (int k = 0; k < cnt; ++k) {
        const float4 c = s_p[w][k];                 // same addr all lanes
        m2 = fminf(m2, c.x * mw0 + c.y * mw1 + c.z * mw2);
    }
    // layer-1 / layer-3 mins: split neighbors across lanes + butterfly
    float m1p = 1e30f, m3p = 1e30f;
    for (int k = lane; k < cnt; k += 64) {
        const float4 c = s_p[w][k];
        m1p = fminf(m1p, c.x * w10 + c.y * w11 + c.z * w12);
        m3p = fminf(m3p, c.x * w30 + c.y * w31 + c.z * w32);
    }
    #pragma unroll
    for (int d = 32; d >= 1; d >>= 1) {
        m1p = fminf(m1p, __shfl_xor(m1p, d, 64));
        m3p = fminf(m3p, __shfl_xor(m3p, d, 64));
    }

    // ---- epilogue (wave-uniform scalars computed redundantly) ----
    const float qx = nodes[3 * i + 0];
    const float qy = nodes[3 * i + 1];
    const float qz = nodes[3 * i + 2];
    const float tp2 = qx * mw0 + qy * mw1 + qz * mw2;
    const float tp1 = qx * w10 + qy * w11 + qz * w12;
    const float tp3 = qx * w30 + qy * w31 + qz * w32;

    const float agg1 = tp1 - m1p + btheta1[0];
    const float h1   = fmaxf(0.f, x[i] * Wphi1[0] + bphi1[0] + agg1);
    const float agg3 = tp3 - m3p + btheta3[0];

    const float agg2 = tp2 - m2 + btheta2[lane];
    const float h2   = fmaxf(0.f, h1 * Wphi2[lane] + bphi2[lane] + agg2);

    float partial = h2 * Wphi3[lane];
    #pragma unroll
    for (int d = 32; d >= 1; d >>= 1)
        partial += __shfl_xor(partial, d, 64);

    if (lane == 0)
        out[i] = 1.f / (1.f + expf(-(partial + bphi3[0] + agg3)));
}

extern "C" void kernel_launch(void* const* d_in, const int* in_sizes, int n_in,
                              void* d_out, int out_size, void* d_ws, size_t ws_size,
                              hipStream_t stream) {
    const float* x         = (const float*)d_in[0];
    const float* nodes     = (const float*)d_in[1];
    const int*   adj       = (const int*)d_in[2];
    const float* Wphi1     = (const float*)d_in[3];
    const float* bphi1     = (const float*)d_in[4];
    const float* Wtheta1   = (const float*)d_in[5];
    const float* btheta1   = (const float*)d_in[6];
    const float* Wphi2     = (const float*)d_in[7];
    const float* bphi2     = (const float*)d_in[8];
    const float* Wtheta2   = (const float*)d_in[9];
    const float* btheta2   = (const float*)d_in[10];
    const float* Wphi3     = (const float*)d_in[11];
    const float* bphi3     = (const float*)d_in[12];
    const float* Wtheta3   = (const float*)d_in[13];
    const float* btheta3   = (const float*)d_in[14];
    float* out = (float*)d_out;

    devgnn_kernel<<<NV / 4, 256, 0, stream>>>(
        x, nodes, adj,
        Wphi1, bphi1, Wtheta1, btheta1,
        Wphi2, bphi2, Wtheta2, btheta2,
        Wphi3, bphi3, Wtheta3, btheta3,
        out);
}

// Round 7
// 47.471 us; speedup vs baseline: 1.7002x; 1.0128x over previous
//
#include <hip/hip_runtime.h>
#include <cstdint>

#define NV 8192
#define CAP 192   // per-row neighbor cap (mean ~33.8, sigma ~5.8)

typedef int v4i __attribute__((ext_vector_type(4)));

__global__ __launch_bounds__(256, 8) void devgnn_kernel(
    const float* __restrict__ x,
    const float* __restrict__ nodes,
    const int*   __restrict__ adj,          // [NV][NV] int32 bool
    const float* __restrict__ Wphi1,   const float* __restrict__ bphi1,
    const float* __restrict__ Wtheta1, const float* __restrict__ btheta1,
    const float* __restrict__ Wphi2,   const float* __restrict__ bphi2,
    const float* __restrict__ Wtheta2, const float* __restrict__ btheta2,
    const float* __restrict__ Wphi3,   const float* __restrict__ bphi3,
    const float* __restrict__ Wtheta3, const float* __restrict__ btheta3,
    float* __restrict__ out)
{
    const int t    = threadIdx.x;
    const int w    = t >> 6;                // wave id 0..3
    const int lane = t & 63;
    const int i    = blockIdx.x * 4 + w;    // this wave's row

    // wave-private LDS slices; zero __syncthreads in the kernel
    __shared__ int    s_nb[4][CAP];
    __shared__ float4 s_p[4][CAP];
    __shared__ int    s_cnt[4];

    if (lane == 0) s_cnt[w] = 0;

    const v4i* row = reinterpret_cast<const v4i*>(adj + (size_t)i * NV);

    // ---- scan: 2048 int4/row in 8 batches of 4 int4/lane, double-buffered.
    // Staging = 32 VGPRs so the kernel fits 64 VGPR -> 32 waves/CU.
    v4i va[4], vb[4];

    auto expand = [&](const v4i* v, int batch) {
        #pragma unroll
        for (int r = 0; r < 4; ++r) {
            const v4i vv = v[r];
            if ((vv[0] | vv[1] | vv[2] | vv[3]) != 0) {
                const int base = (batch * 256 + lane + r * 64) * 4;
                #pragma unroll
                for (int k = 0; k < 4; ++k) {
                    if (vv[k]) {
                        const int p = atomicAdd(&s_cnt[w], 1);
                        if (p < CAP) s_nb[w][p] = base + k;
                    }
                }
            }
        }
    };

    #pragma unroll
    for (int r = 0; r < 4; ++r) va[r] = row[lane + r * 64];              // b0
    #pragma unroll
    for (int r = 0; r < 4; ++r) vb[r] = row[256 + lane + r * 64];        // b1
    expand(va, 0);
    #pragma unroll
    for (int r = 0; r < 4; ++r) va[r] = row[512 + lane + r * 64];        // b2
    expand(vb, 1);
    #pragma unroll
    for (int r = 0; r < 4; ++r) vb[r] = row[768 + lane + r * 64];        // b3
    expand(va, 2);
    #pragma unroll
    for (int r = 0; r < 4; ++r) va[r] = row[1024 + lane + r * 64];       // b4
    expand(vb, 3);
    #pragma unroll
    for (int r = 0; r < 4; ++r) vb[r] = row[1280 + lane + r * 64];       // b5
    expand(va, 4);
    #pragma unroll
    for (int r = 0; r < 4; ++r) va[r] = row[1536 + lane + r * 64];       // b6
    expand(vb, 5);
    #pragma unroll
    for (int r = 0; r < 4; ++r) vb[r] = row[1792 + lane + r * 64];       // b7
    expand(va, 6);
    expand(vb, 7);

    int cnt = s_cnt[w];
    cnt = (cnt < CAP) ? cnt : CAP;

    // ---- gather neighbor coords (scattered, L2-hot) ----
    for (int k = lane; k < cnt; k += 64) {
        const int j = s_nb[w][k];
        s_p[w][k] = make_float4(nodes[3 * j + 0],
                                nodes[3 * j + 1],
                                nodes[3 * j + 2], 0.f);
    }

    // ---- per-lane channel weights loaded AFTER the scan (short live range) ----
    const float mw0 = Wtheta2[lane];        // Wtheta2 is [3][64] row-major
    const float mw1 = Wtheta2[64 + lane];
    const float mw2 = Wtheta2[128 + lane];
    const float w10 = Wtheta1[0], w11 = Wtheta1[1], w12 = Wtheta1[2];
    const float w30 = Wtheta3[0], w31 = Wtheta3[1], w32 = Wtheta3[2];

    // ---- channel mins: lane = layer-2 channel (broadcast reads) ----
    float m2 = 1e30f;
    for (int k = 0; k < cnt; ++k) {
        const float4 c = s_p[w][k];                 // same addr all lanes
        m2 = fminf(m2, c.x * mw0 + c.y * mw1 + c.z * mw2);
    }
    // layer-1 / layer-3 mins: neighbors split across lanes + butterfly
    float m1p = 1e30f, m3p = 1e30f;
    for (int k = lane; k < cnt; k += 64) {
        const float4 c = s_p[w][k];
        m1p = fminf(m1p, c.x * w10 + c.y * w11 + c.z * w12);
        m3p = fminf(m3p, c.x * w30 + c.y * w31 + c.z * w32);
    }
    #pragma unroll
    for (int d = 32; d >= 1; d >>= 1) {
        m1p = fminf(m1p, __shfl_xor(m1p, d, 64));
        m3p = fminf(m3p, __shfl_xor(m3p, d, 64));
    }

    // ---- epilogue ----
    const float qx = nodes[3 * i + 0];
    const float qy = nodes[3 * i + 1];
    const float qz = nodes[3 * i + 2];
    const float tp2 = qx * mw0 + qy * mw1 + qz * mw2;
    const float tp1 = qx * w10 + qy * w11 + qz * w12;
    const float tp3 = qx * w30 + qy * w31 + qz * w32;

    const float agg1 = tp1 - m1p + btheta1[0];
    const float h1   = fmaxf(0.f, x[i] * Wphi1[0] + bphi1[0] + agg1);
    const float agg3 = tp3 - m3p + btheta3[0];

    const float agg2 = tp2 - m2 + btheta2[lane];
    const float h2   = fmaxf(0.f, h1 * Wphi2[lane] + bphi2[lane] + agg2);

    float partial = h2 * Wphi3[lane];
    #pragma unroll
    for (int d = 32; d >= 1; d >>= 1)
        partial += __shfl_xor(partial, d, 64);

    if (lane == 0)
        out[i] = 1.f / (1.f + expf(-(partial + bphi3[0] + agg3)));
}

extern "C" void kernel_launch(void* const* d_in, const int* in_sizes, int n_in,
                              void* d_out, int out_size, void* d_ws, size_t ws_size,
                              hipStream_t stream) {
    const float* x         = (const float*)d_in[0];
    const float* nodes     = (const float*)d_in[1];
    const int*   adj       = (const int*)d_in[2];
    const float* Wphi1     = (const float*)d_in[3];
    const float* bphi1     = (const float*)d_in[4];
    const float* Wtheta1   = (const float*)d_in[5];
    const float* btheta1   = (const float*)d_in[6];
    const float* Wphi2     = (const float*)d_in[7];
    const float* bphi2     = (const float*)d_in[8];
    const float* Wtheta2   = (const float*)d_in[9];
    const float* btheta2   = (const float*)d_in[10];
    const float* Wphi3     = (const float*)d_in[11];
    const float* bphi3     = (const float*)d_in[12];
    const float* Wtheta3   = (const float*)d_in[13];
    const float* btheta3   = (const float*)d_in[14];
    float* out = (float*)d_out;

    devgnn_kernel<<<NV / 4, 256, 0, stream>>>(
        x, nodes, adj,
        Wphi1, bphi1, Wtheta1, btheta1,
        Wphi2, bphi2, Wtheta2, btheta2,
        Wphi3, bphi3, Wtheta3, btheta3,
        out);
}